// Round 8
// baseline (160.262 us; speedup 1.0000x reference)
//
#include <hip/hip_runtime.h>
#include <cstdint>

#define DIMD 1024
#define NROWS 8192
#define KDIM 2048   // 2*DIM

typedef unsigned short u16;
typedef __bf16 bf16x8 __attribute__((ext_vector_type(8)));
typedef float f32x4 __attribute__((ext_vector_type(4)));

__device__ __forceinline__ u16 f2bf(float f) {
  unsigned u = __builtin_bit_cast(unsigned, f);
  return (u16)((u + 0x7FFFu + ((u >> 16) & 1u)) >> 16);  // RNE
}

// Branch-free exact-enough GELU (A&S 7.1.26 erf, |err| <= 1.5e-7).
__device__ __forceinline__ float gelu_exact(float x) {
  float s = 0.70710678118654752f * x;
  float a = fabsf(s);
  float k = __fdividef(1.0f, fmaf(0.3275911f, a, 1.0f));
  float p = 1.061405429f;
  p = fmaf(p, k, -1.453152027f);
  p = fmaf(p, k, 1.421413741f);
  p = fmaf(p, k, -0.284496736f);
  p = fmaf(p, k, 0.254829592f);
  p = p * k;
  float e = __expf(-s * s);
  float erf_s = copysignf(fmaf(-p, e, 1.0f), s);
  return 0.5f * x * (1.0f + erf_s);
}

// ---------------------------------------------------------------------------
// pre_kernel v2 (unchanged): conv(3x5)+bias+gelu -> x2 bf16, w2 cast.
// ---------------------------------------------------------------------------
__global__ __launch_bounds__(256) void pre_kernel(
    const float* __restrict__ ifeats, const float* __restrict__ tn,
    const float* __restrict__ ta, const float* __restrict__ cw,
    const float* __restrict__ cb, const float* __restrict__ w2,
    u16* __restrict__ x2, u16* __restrict__ w2b) {
  const int b = blockIdx.x;
  const int t = threadIdx.x;
  if (b < 1024) {                  // 8 rows per block
    const int c = t >> 7;          // out channel 0/1
    const int w0 = (t & 127) << 3; // 8 outputs starting here
    float cwn[5], cwa[5], cwi[5];
#pragma unroll
    for (int k = 0; k < 5; ++k) {
      cwn[k] = cw[c * 15 + k];
      cwa[k] = cw[c * 15 + 5 + k];
      cwi[k] = cw[c * 15 + 10 + k];
    }
    const float bias = cb[c];
    float base[8];
    {
      float wn[12], wa[12];
#pragma unroll
      for (int j = 0; j < 12; ++j) {
        int wp = w0 - 2 + j;
        bool ok = (wp >= 0) && (wp < DIMD);
        wn[j] = ok ? tn[ok ? wp : 0] : 0.f;
        wa[j] = ok ? ta[ok ? wp : 0] : 0.f;
      }
#pragma unroll
      for (int s = 0; s < 8; ++s) {
        float x = bias;
#pragma unroll
        for (int k = 0; k < 5; ++k) {
          x = fmaf(cwn[k], wn[s + k], x);
          x = fmaf(cwa[k], wa[s + k], x);
        }
        base[s] = x;
      }
    }
    const bool has_l = (w0 > 0);
    const bool has_r = (w0 < DIMD - 8);
#pragma unroll 1
    for (int r = 0; r < 8; ++r) {
      const int row = b * 8 + r;
      const float* irow = ifeats + (size_t)row * DIMD;
      float wi[12];
      float4 m0 = *(const float4*)(irow + w0);
      float4 m1 = *(const float4*)(irow + w0 + 4);
      wi[0] = has_l ? irow[w0 - 2] : 0.f;
      wi[1] = has_l ? irow[w0 - 1] : 0.f;
      wi[2] = m0.x; wi[3] = m0.y; wi[4] = m0.z; wi[5] = m0.w;
      wi[6] = m1.x; wi[7] = m1.y; wi[8] = m1.z; wi[9] = m1.w;
      wi[10] = has_r ? irow[w0 + 8] : 0.f;
      wi[11] = has_r ? irow[w0 + 9] : 0.f;
      union { u16 o[8]; uint4 u; } pk;
#pragma unroll
      for (int s = 0; s < 8; ++s) {
        float x = base[s];
#pragma unroll
        for (int k = 0; k < 5; ++k) x = fmaf(cwi[k], wi[s + k], x);
        pk.o[s] = f2bf(gelu_exact(x));
      }
      *(uint4*)(x2 + (size_t)row * KDIM + c * DIMD + w0) = pk.u;
    }
  } else {
    const int t2 = (b - 1024) * 256 + t;
    const float4* p = (const float4*)(w2 + (size_t)t2 * 8);
    float4 a = p[0], bb = p[1];
    union { u16 o[8]; uint4 v; } pk;
    pk.o[0] = f2bf(a.x);  pk.o[1] = f2bf(a.y);  pk.o[2] = f2bf(a.z);  pk.o[3] = f2bf(a.w);
    pk.o[4] = f2bf(bb.x); pk.o[5] = f2bf(bb.y); pk.o[6] = f2bf(bb.z); pk.o[7] = f2bf(bb.w);
    *(uint4*)(w2b + (size_t)t2 * 8) = pk.v;
  }
}

// ---------------------------------------------------------------------------
// GEMM v9 = r7 (44.2us, verified) + epilogue-ifeats register prefetch.
//   r7 split: K-loop ~33us (near LDS-pipe model 1920 cyc/tile) + ~10-11us
//   serial epilogue (ifeats 32MB read + out 32MB write, HBM-bound, 1
//   block/CU -> no cross-block overlap). K-loop HBM util is only 25% ->
//   ~4 TB/s spare: prefetch each thread's 64 ifeats f32 into registers,
//   4 scalar loads/tile over tiles 14..29 (hand-unrolled so fv[] indices
//   are compile-time -> registers, not scratch). Epilogue then only writes.
//   vmcnt re-derived: ifeats issued BEFORE staging in a tile, so end-of-tile
//   queue = [st(t+2), if_t(4), st(t+3)(6)] -> vmcnt(10) drains exactly
//   st(t+2), keeps both newer groups. t=29: vmcnt(4) (drains st(31), keeps
//   if_29). t=30,31: vmcnt(0). Tiles 0..13 unchanged (vmcnt(6)).
// ---------------------------------------------------------------------------
__device__ __forceinline__ void gl_lds16(const u16* g, u16* l) {
  __builtin_amdgcn_global_load_lds(
      (__attribute__((address_space(1))) void*)g,
      (__attribute__((address_space(3))) void*)l, 16, 0, 0);
}

#define BK 64       // u16 per row per K-tile
#define BM 256
#define BN 128
#define NTILE 32    // KDIM / BK

#define VMW(N) asm volatile("s_waitcnt vmcnt(" #N ")" ::: "memory")

// One K-tile. AVC/BVC: frag set for MFMA(T). AVN/BVN: filled for T+1.
// FNEXT/STG/PRE: compile-time 0/1 flags. E0: fv base index (literal).
// VMN: vmcnt immediate (literal).
#define GITER2(T, AVC, BVC, AVN, BVN, FNEXT, STG, PRE, E0, VMN)                \
  {                                                                            \
    if (FNEXT) {                                                               \
      _Pragma("unroll") for (int mt = 0; mt < 4; ++mt)                         \
        _Pragma("unroll") for (int ks = 0; ks < 2; ++ks)                       \
          AVN[mt][ks] = *(const bf16x8*)&pa1[(wm + mt * 16 + r16) * BK +       \
                                             (((ks * 4 + quad) ^ sw) << 3)];   \
      _Pragma("unroll") for (int nt = 0; nt < 4; ++nt)                         \
        _Pragma("unroll") for (int ks = 0; ks < 2; ++ks)                       \
          BVN[nt][ks] = *(const bf16x8*)&pb1[(wn + nt * 16 + r16) * BK +       \
                                             (((ks * 4 + quad) ^ sw) << 3)];   \
    }                                                                          \
    if (PRE) {                                                                 \
      const int e_mt = (E0) >> 4;                                              \
      const int e_nt = ((E0) >> 2) & 3;                                        \
      _Pragma("unroll") for (int r = 0; r < 4; ++r)                            \
        fv[(E0) + r] = ifeats[(size_t)(i0 + wm + e_mt * 16 + quad * 4 + r) *   \
                                  DIMD + j0 + wn + e_nt * 16 + r16];           \
    }                                                                          \
    if (STG) {                                                                 \
      _Pragma("unroll") for (int u = 0; u < 4; ++u)                            \
        gl_lds16(gA[u] + ((T) + 3) * BK, pa0 + (wv * 32 + u * 8) * BK);        \
      _Pragma("unroll") for (int u = 0; u < 2; ++u)                            \
        gl_lds16(gB[u] + ((T) + 3) * BK, pb0 + (wv * 16 + u * 8) * BK);        \
    }                                                                          \
    __builtin_amdgcn_sched_barrier(0);                                         \
    __builtin_amdgcn_s_setprio(1);                                             \
    _Pragma("unroll") for (int ks = 0; ks < 2; ++ks)                           \
      _Pragma("unroll") for (int mt = 0; mt < 4; ++mt)                         \
        _Pragma("unroll") for (int nt = 0; nt < 4; ++nt)                       \
          acc[mt][nt] = __builtin_amdgcn_mfma_f32_16x16x32_bf16(               \
              AVC[mt][ks], BVC[nt][ks], acc[mt][nt], 0, 0, 0);                 \
    __builtin_amdgcn_s_setprio(0);                                             \
    VMW(VMN);                                                                  \
    asm volatile("s_waitcnt lgkmcnt(0)" ::: "memory");                         \
    __builtin_amdgcn_s_barrier();                                              \
    __builtin_amdgcn_sched_barrier(0);                                         \
    u16* x_;                                                                   \
    x_ = pa0; pa0 = pa1; pa1 = pa2; pa2 = x_;                                  \
    x_ = pb0; pb0 = pb1; pb1 = pb2; pb2 = x_;                                  \
  }

__global__ __launch_bounds__(512, 1) void gemm_bt(
    const u16* __restrict__ A,      // x2 bf16 [8192, 2048]
    const u16* __restrict__ B,      // w2 bf16 [1024, 2048]
    const float* __restrict__ ifeats,
    const float* __restrict__ b2,
    float* __restrict__ out) {
  constexpr int K = KDIM;
  __shared__ __align__(16) u16 sA[3][BM * BK];  // 3 x 32 KB
  __shared__ __align__(16) u16 sB[3][BN * BK];  // 3 x 16 KB; 144 KB total

  const int tid = threadIdx.x;
  const int wv = tid >> 6;         // wave 0..7
  const int lane = tid & 63;
  // XCD swizzle: 256 blocks; xcd = id&7 owns 4 M-strips x 8 N-blocks.
  const int id = blockIdx.x;       // 0..255
  const int xcd = id & 7;
  const int s_ = id >> 3;          // 0..31
  const int i0 = (xcd * 4 + (s_ >> 3)) * BM;
  const int j0 = (s_ & 7) * BN;

  const int wm = (wv >> 1) * 64;   // wave tile 64x64; 4M x 2N wave grid
  const int wn = (wv & 1) * 64;
  const int quad = lane >> 4;
  const int r16 = lane & 15;
  const int sw = r16 & 7;

  // staging: unit = 8 rows x 128 B = one gl_lds16. A 4 units/wave, B 2.
  const int srow = lane >> 3;                 // 0..7
  const int schunk = (lane & 7) ^ srow;       // XOR-swizzled 16B chunk
  const u16* gA[4];
  const u16* gB[2];
#pragma unroll
  for (int u = 0; u < 4; ++u)
    gA[u] = A + (size_t)(i0 + wv * 32 + u * 8 + srow) * K + schunk * 8;
#pragma unroll
  for (int u = 0; u < 2; ++u)
    gB[u] = B + (size_t)(j0 + wv * 16 + u * 8 + srow) * K + schunk * 8;

  const f32x4 vzero = {0.f, 0.f, 0.f, 0.f};
  f32x4 acc[4][4];
#pragma unroll
  for (int a = 0; a < 4; ++a)
#pragma unroll
    for (int b = 0; b < 4; ++b) acc[a][b] = vzero;

  float fv[64];                    // epilogue ifeats prefetch (static-indexed)

  u16* pa0 = (u16*)sA[0]; u16* pa1 = (u16*)sA[1]; u16* pa2 = (u16*)sA[2];
  u16* pb0 = (u16*)sB[0]; u16* pb1 = (u16*)sB[1]; u16* pb2 = (u16*)sB[2];

  bf16x8 avX[4][2], bvX[4][2], avY[4][2], bvY[4][2];

  // Prologue: tiles 0,1,2 -> bufs 0,1,2 (6 loads/thread each).
#pragma unroll
  for (int tt = 0; tt < 3; ++tt) {
    u16* ba = (tt == 0) ? pa0 : (tt == 1) ? pa1 : pa2;
    u16* bb = (tt == 0) ? pb0 : (tt == 1) ? pb1 : pb2;
#pragma unroll
    for (int u = 0; u < 4; ++u)
      gl_lds16(gA[u] + tt * BK, ba + (wv * 32 + u * 8) * BK);
#pragma unroll
    for (int u = 0; u < 2; ++u)
      gl_lds16(gB[u] + tt * BK, bb + (wv * 16 + u * 8) * BK);
  }
  asm volatile("s_waitcnt vmcnt(6)" ::: "memory");   // tiles 0,1 resident
  __builtin_amdgcn_s_barrier();
  // frags(0) -> X
#pragma unroll
  for (int mt = 0; mt < 4; ++mt)
#pragma unroll
    for (int ks = 0; ks < 2; ++ks)
      avX[mt][ks] = *(const bf16x8*)&pa0[(wm + mt * 16 + r16) * BK +
                                         (((ks * 4 + quad) ^ sw) << 3)];
#pragma unroll
  for (int nt = 0; nt < 4; ++nt)
#pragma unroll
    for (int ks = 0; ks < 2; ++ks)
      bvX[nt][ks] = *(const bf16x8*)&pb0[(wn + nt * 16 + r16) * BK +
                                         (((ks * 4 + quad) ^ sw) << 3)];
  asm volatile("s_waitcnt lgkmcnt(0)" ::: "memory");
  __builtin_amdgcn_s_barrier();
  __builtin_amdgcn_sched_barrier(0);

  // Tiles 0..13: runtime loop, no ifeats prefetch, vmcnt(6) (r7-identical).
  for (int t = 0; t < 14; t += 2) {
    GITER2(t,     avX, bvX, avY, bvY, 1, 1, 0, 0, 6);
    GITER2(t + 1, avY, bvY, avX, bvX, 1, 1, 0, 0, 6);
  }
  // Tiles 14..31: unrolled; ifeats prefetch 4/tile over 14..29.
  GITER2(14, avX, bvX, avY, bvY, 1, 1, 1,  0, 10);
  GITER2(15, avY, bvY, avX, bvX, 1, 1, 1,  4, 10);
  GITER2(16, avX, bvX, avY, bvY, 1, 1, 1,  8, 10);
  GITER2(17, avY, bvY, avX, bvX, 1, 1, 1, 12, 10);
  GITER2(18, avX, bvX, avY, bvY, 1, 1, 1, 16, 10);
  GITER2(19, avY, bvY, avX, bvX, 1, 1, 1, 20, 10);
  GITER2(20, avX, bvX, avY, bvY, 1, 1, 1, 24, 10);
  GITER2(21, avY, bvY, avX, bvX, 1, 1, 1, 28, 10);
  GITER2(22, avX, bvX, avY, bvY, 1, 1, 1, 32, 10);
  GITER2(23, avY, bvY, avX, bvX, 1, 1, 1, 36, 10);
  GITER2(24, avX, bvX, avY, bvY, 1, 1, 1, 40, 10);
  GITER2(25, avY, bvY, avX, bvX, 1, 1, 1, 44, 10);
  GITER2(26, avX, bvX, avY, bvY, 1, 1, 1, 48, 10);
  GITER2(27, avY, bvY, avX, bvX, 1, 1, 1, 52, 10);
  GITER2(28, avX, bvX, avY, bvY, 1, 1, 1, 56, 10);
  GITER2(29, avY, bvY, avX, bvX, 1, 0, 1, 60, 4);
  GITER2(30, avX, bvX, avY, bvY, 1, 0, 0,  0, 0);
  GITER2(31, avY, bvY, avX, bvX, 0, 0, 0,  0, 0);

  // epilogue: C/D layout col=lane&15, row=quad*4+reg; ifeats from fv[].
#pragma unroll
  for (int nt = 0; nt < 4; ++nt) {
    int col = j0 + wn + nt * 16 + r16;
    float bias = b2[col];
#pragma unroll
    for (int mt = 0; mt < 4; ++mt) {
      int rbase = i0 + wm + mt * 16 + quad * 4;
#pragma unroll
      for (int r = 0; r < 4; ++r) {
        size_t idx = (size_t)(rbase + r) * DIMD + col;
        out[idx] = fv[mt * 16 + nt * 4 + r] + bias + acc[mt][nt][r];
      }
    }
  }
}

// ---------------------------------------------------------------------------
extern "C" void kernel_launch(void* const* d_in, const int* in_sizes, int n_in,
                              void* d_out, int out_size, void* d_ws, size_t ws_size,
                              hipStream_t stream) {
  const float* ifeats = (const float*)d_in[0];
  const float* tn     = (const float*)d_in[1];
  const float* ta     = (const float*)d_in[2];
  const float* cw     = (const float*)d_in[3];
  const float* cb     = (const float*)d_in[4];
  const float* w2     = (const float*)d_in[5];
  const float* b2     = (const float*)d_in[6];
  float* out = (float*)d_out;

  // ws: [0, 4MB) w2 bf16 | [4MB, 36MB) x2 bf16
  u16* w2b = (u16*)d_ws;
  u16* x2  = (u16*)((char*)d_ws + (size_t)DIMD * KDIM * 2);

  pre_kernel<<<2048, 256, 0, stream>>>(ifeats, tn, ta, cw, cb, w2, x2, w2b);
  gemm_bt<<<256, 512, 0, stream>>>(x2, w2b, ifeats, b2, out);
}

// Round 9
// 150.649 us; speedup vs baseline: 1.0638x; 1.0638x over previous
//
#include <hip/hip_runtime.h>
#include <cstdint>

#define DIMD 1024
#define NROWS 8192
#define KDIM 2048   // 2*DIM

typedef unsigned short u16;
typedef __bf16 bf16x8 __attribute__((ext_vector_type(8)));
typedef float f32x4 __attribute__((ext_vector_type(4)));

__device__ __forceinline__ u16 f2bf(float f) {
  unsigned u = __builtin_bit_cast(unsigned, f);
  return (u16)((u + 0x7FFFu + ((u >> 16) & 1u)) >> 16);  // RNE
}

// Branch-free exact-enough GELU (A&S 7.1.26 erf, |err| <= 1.5e-7).
__device__ __forceinline__ float gelu_exact(float x) {
  float s = 0.70710678118654752f * x;
  float a = fabsf(s);
  float k = __fdividef(1.0f, fmaf(0.3275911f, a, 1.0f));
  float p = 1.061405429f;
  p = fmaf(p, k, -1.453152027f);
  p = fmaf(p, k, 1.421413741f);
  p = fmaf(p, k, -0.284496736f);
  p = fmaf(p, k, 0.254829592f);
  p = p * k;
  float e = __expf(-s * s);
  float erf_s = copysignf(fmaf(-p, e, 1.0f), s);
  return 0.5f * x * (1.0f + erf_s);
}

// ---------------------------------------------------------------------------
// pre_kernel v2 (unchanged): conv(3x5)+bias+gelu -> x2 bf16, w2 cast.
// ---------------------------------------------------------------------------
__global__ __launch_bounds__(256) void pre_kernel(
    const float* __restrict__ ifeats, const float* __restrict__ tn,
    const float* __restrict__ ta, const float* __restrict__ cw,
    const float* __restrict__ cb, const float* __restrict__ w2,
    u16* __restrict__ x2, u16* __restrict__ w2b) {
  const int b = blockIdx.x;
  const int t = threadIdx.x;
  if (b < 1024) {                  // 8 rows per block
    const int c = t >> 7;          // out channel 0/1
    const int w0 = (t & 127) << 3; // 8 outputs starting here
    float cwn[5], cwa[5], cwi[5];
#pragma unroll
    for (int k = 0; k < 5; ++k) {
      cwn[k] = cw[c * 15 + k];
      cwa[k] = cw[c * 15 + 5 + k];
      cwi[k] = cw[c * 15 + 10 + k];
    }
    const float bias = cb[c];
    float base[8];
    {
      float wn[12], wa[12];
#pragma unroll
      for (int j = 0; j < 12; ++j) {
        int wp = w0 - 2 + j;
        bool ok = (wp >= 0) && (wp < DIMD);
        wn[j] = ok ? tn[ok ? wp : 0] : 0.f;
        wa[j] = ok ? ta[ok ? wp : 0] : 0.f;
      }
#pragma unroll
      for (int s = 0; s < 8; ++s) {
        float x = bias;
#pragma unroll
        for (int k = 0; k < 5; ++k) {
          x = fmaf(cwn[k], wn[s + k], x);
          x = fmaf(cwa[k], wa[s + k], x);
        }
        base[s] = x;
      }
    }
    const bool has_l = (w0 > 0);
    const bool has_r = (w0 < DIMD - 8);
#pragma unroll 1
    for (int r = 0; r < 8; ++r) {
      const int row = b * 8 + r;
      const float* irow = ifeats + (size_t)row * DIMD;
      float wi[12];
      float4 m0 = *(const float4*)(irow + w0);
      float4 m1 = *(const float4*)(irow + w0 + 4);
      wi[0] = has_l ? irow[w0 - 2] : 0.f;
      wi[1] = has_l ? irow[w0 - 1] : 0.f;
      wi[2] = m0.x; wi[3] = m0.y; wi[4] = m0.z; wi[5] = m0.w;
      wi[6] = m1.x; wi[7] = m1.y; wi[8] = m1.z; wi[9] = m1.w;
      wi[10] = has_r ? irow[w0 + 8] : 0.f;
      wi[11] = has_r ? irow[w0 + 9] : 0.f;
      union { u16 o[8]; uint4 u; } pk;
#pragma unroll
      for (int s = 0; s < 8; ++s) {
        float x = base[s];
#pragma unroll
        for (int k = 0; k < 5; ++k) x = fmaf(cwi[k], wi[s + k], x);
        pk.o[s] = f2bf(gelu_exact(x));
      }
      *(uint4*)(x2 + (size_t)row * KDIM + c * DIMD + w0) = pk.u;
    }
  } else {
    const int t2 = (b - 1024) * 256 + t;
    const float4* p = (const float4*)(w2 + (size_t)t2 * 8);
    float4 a = p[0], bb = p[1];
    union { u16 o[8]; uint4 v; } pk;
    pk.o[0] = f2bf(a.x);  pk.o[1] = f2bf(a.y);  pk.o[2] = f2bf(a.z);  pk.o[3] = f2bf(a.w);
    pk.o[4] = f2bf(bb.x); pk.o[5] = f2bf(bb.y); pk.o[6] = f2bf(bb.z); pk.o[7] = f2bf(bb.w);
    *(uint4*)(w2b + (size_t)t2 * 8) = pk.v;
  }
}

// ---------------------------------------------------------------------------
// GEMM v10 = r7 (44.2us verified) + epilogue-ifeats prefetch into FREED LDS.
//   r8 lesson: fv[64] in VGPRs spilled to scratch (VGPR stayed 128,
//   WRITE_SIZE doubled) -> destination must be LDS, which costs 0 registers.
//   The 3-deep rotation frees tile-t's buffers once frags(t) are in regs:
//     iter 29 frees sA[2] (phys bytes 64..96K -> ifeats rows 128..191)
//     iter 30 frees sA[0] (rows 0..63)   + sB[0] (rows 192..223)
//     iter 31 frees sA[1] (rows 64..127) + sB[1] (rows 224..255)
//   ifeats tile (256 rows x 128 f32 = 128 KB) overlays smem rows r at u16
//   offset r*256. gl_lds16: wave-uniform base (2 rows/wave), lane-linear
//   dest; per-lane SOURCE pre-swizzled chunk^(row&7) so the epilogue's
//   quad-strided reads are 2-way bank-aliased (free) instead of 4-way.
//   vmcnt per tail iter: end-28 vmcnt(6) [drain st(30)]; end-29 vmcnt(4)
//   [drain st(31), keep IF1(4)]; end-30 vmcnt(10) [keep IF1+IF2]; end-31
//   vmcnt(0) [all ifeats resident]. Only IF3 (~48 KB under the last MFMA
//   phase) is partially exposed.
// ---------------------------------------------------------------------------
__device__ __forceinline__ void gl_lds16(const u16* g, u16* l) {
  __builtin_amdgcn_global_load_lds(
      (__attribute__((address_space(1))) void*)g,
      (__attribute__((address_space(3))) void*)l, 16, 0, 0);
}

#define BK 64       // u16 per row per K-tile
#define BM 256
#define BN 128
#define NTILE 32    // KDIM / BK

#define VMW(N) asm volatile("s_waitcnt vmcnt(" #N ")" ::: "memory")

// One K-tile. AVC/BVC: frag set for MFMA(T). AVN/BVN: filled for T+1.
// FNEXT/STG: compile-time 0/1. VMN: vmcnt literal. __VA_ARGS__: extra
// issue code (ifeats LDS prefetch) placed with the staging section.
#define GITER(T, AVC, BVC, AVN, BVN, FNEXT, STG, VMN, ...)                     \
  {                                                                            \
    if (FNEXT) {                                                               \
      _Pragma("unroll") for (int mt = 0; mt < 4; ++mt)                         \
        _Pragma("unroll") for (int ks = 0; ks < 2; ++ks)                       \
          AVN[mt][ks] = *(const bf16x8*)&pa1[(wm + mt * 16 + r16) * BK +       \
                                             (((ks * 4 + quad) ^ sw) << 3)];   \
      _Pragma("unroll") for (int nt = 0; nt < 4; ++nt)                         \
        _Pragma("unroll") for (int ks = 0; ks < 2; ++ks)                       \
          BVN[nt][ks] = *(const bf16x8*)&pb1[(wn + nt * 16 + r16) * BK +       \
                                             (((ks * 4 + quad) ^ sw) << 3)];   \
    }                                                                          \
    __VA_ARGS__;                                                               \
    if (STG) {                                                                 \
      _Pragma("unroll") for (int u = 0; u < 4; ++u)                            \
        gl_lds16(gA[u] + ((T) + 3) * BK, pa0 + (wv * 32 + u * 8) * BK);        \
      _Pragma("unroll") for (int u = 0; u < 2; ++u)                            \
        gl_lds16(gB[u] + ((T) + 3) * BK, pb0 + (wv * 16 + u * 8) * BK);        \
    }                                                                          \
    __builtin_amdgcn_sched_barrier(0);                                         \
    __builtin_amdgcn_s_setprio(1);                                             \
    _Pragma("unroll") for (int ks = 0; ks < 2; ++ks)                           \
      _Pragma("unroll") for (int mt = 0; mt < 4; ++mt)                         \
        _Pragma("unroll") for (int nt = 0; nt < 4; ++nt)                       \
          acc[mt][nt] = __builtin_amdgcn_mfma_f32_16x16x32_bf16(               \
              AVC[mt][ks], BVC[nt][ks], acc[mt][nt], 0, 0, 0);                 \
    __builtin_amdgcn_s_setprio(0);                                             \
    VMW(VMN);                                                                  \
    asm volatile("s_waitcnt lgkmcnt(0)" ::: "memory");                         \
    __builtin_amdgcn_s_barrier();                                              \
    __builtin_amdgcn_sched_barrier(0);                                         \
    u16* x_;                                                                   \
    x_ = pa0; pa0 = pa1; pa1 = pa2; pa2 = x_;                                  \
    x_ = pb0; pb0 = pb1; pb1 = pb2; pb2 = x_;                                  \
  }

__global__ __launch_bounds__(512, 1) void gemm_bt(
    const u16* __restrict__ A,      // x2 bf16 [8192, 2048]
    const u16* __restrict__ B,      // w2 bf16 [1024, 2048]
    const float* __restrict__ ifeats,
    const float* __restrict__ b2,
    float* __restrict__ out) {
  constexpr int K = KDIM;
  // Unified LDS: sA[i] at u16 {0,16384,32768}, sB[i] at {49152,57344,65536}.
  // ifeats overlay: row r (0..255) at u16 r*256 (bytes r*512), total 128 KB.
  __shared__ __align__(16) u16 smem[73728];   // 144 KB

  const int tid = threadIdx.x;
  const int wv = tid >> 6;         // wave 0..7
  const int lane = tid & 63;
  // XCD swizzle: 256 blocks; xcd = id&7 owns 4 M-strips x 8 N-blocks.
  const int id = blockIdx.x;       // 0..255
  const int xcd = id & 7;
  const int s_ = id >> 3;          // 0..31
  const int i0 = (xcd * 4 + (s_ >> 3)) * BM;
  const int j0 = (s_ & 7) * BN;

  const int wm = (wv >> 1) * 64;   // wave tile 64x64; 4M x 2N wave grid
  const int wn = (wv & 1) * 64;
  const int quad = lane >> 4;
  const int r16 = lane & 15;
  const int sw = r16 & 7;

  // staging: unit = 8 rows x 128 B = one gl_lds16. A 4 units/wave, B 2.
  const int srow = lane >> 3;                 // 0..7
  const int schunk = (lane & 7) ^ srow;       // XOR-swizzled 16B chunk
  const u16* gA[4];
  const u16* gB[2];
#pragma unroll
  for (int u = 0; u < 4; ++u)
    gA[u] = A + (size_t)(i0 + wv * 32 + u * 8 + srow) * K + schunk * 8;
#pragma unroll
  for (int u = 0; u < 2; ++u)
    gB[u] = B + (size_t)(j0 + wv * 16 + u * 8 + srow) * K + schunk * 8;

  const f32x4 vzero = {0.f, 0.f, 0.f, 0.f};
  f32x4 acc[4][4];
#pragma unroll
  for (int a = 0; a < 4; ++a)
#pragma unroll
    for (int b = 0; b < 4; ++b) acc[a][b] = vzero;

  u16* pa0 = smem;         u16* pa1 = smem + 16384; u16* pa2 = smem + 32768;
  u16* pb0 = smem + 49152; u16* pb1 = smem + 57344; u16* pb2 = smem + 65536;

  // ifeats->LDS prefetch: one gl_lds16/thread = 16 rows (2 rows/wave).
  // Lane l covers row r0+wv*2+(l>>5), 16B chunk l&31, which must CONTAIN
  // global chunk (l&31)^(row&7)  (read-side XOR swizzle, 4-way -> 2-way).
  auto if_stage = [&](int r0) {
    const int row = r0 + wv * 2 + (lane >> 5);
    const int gch = (lane & 31) ^ (row & 7);
    gl_lds16((const u16*)(ifeats + (size_t)(i0 + row) * DIMD + j0 + gch * 4),
             smem + (size_t)(r0 + wv * 2) * 256);
  };

  bf16x8 avX[4][2], bvX[4][2], avY[4][2], bvY[4][2];

  // Prologue: tiles 0,1,2 -> bufs 0,1,2 (6 loads/thread each).
#pragma unroll
  for (int tt = 0; tt < 3; ++tt) {
    u16* ba = (tt == 0) ? pa0 : (tt == 1) ? pa1 : pa2;
    u16* bb = (tt == 0) ? pb0 : (tt == 1) ? pb1 : pb2;
#pragma unroll
    for (int u = 0; u < 4; ++u)
      gl_lds16(gA[u] + tt * BK, ba + (wv * 32 + u * 8) * BK);
#pragma unroll
    for (int u = 0; u < 2; ++u)
      gl_lds16(gB[u] + tt * BK, bb + (wv * 16 + u * 8) * BK);
  }
  asm volatile("s_waitcnt vmcnt(6)" ::: "memory");   // tiles 0,1 resident
  __builtin_amdgcn_s_barrier();
  // frags(0) -> X
#pragma unroll
  for (int mt = 0; mt < 4; ++mt)
#pragma unroll
    for (int ks = 0; ks < 2; ++ks)
      avX[mt][ks] = *(const bf16x8*)&pa0[(wm + mt * 16 + r16) * BK +
                                         (((ks * 4 + quad) ^ sw) << 3)];
#pragma unroll
  for (int nt = 0; nt < 4; ++nt)
#pragma unroll
    for (int ks = 0; ks < 2; ++ks)
      bvX[nt][ks] = *(const bf16x8*)&pb0[(wn + nt * 16 + r16) * BK +
                                         (((ks * 4 + quad) ^ sw) << 3)];
  asm volatile("s_waitcnt lgkmcnt(0)" ::: "memory");
  __builtin_amdgcn_s_barrier();
  __builtin_amdgcn_sched_barrier(0);

  // Iters 0..27: steady state (stage t+3, vmcnt(6)), r7-identical.
  for (int t = 0; t < 28; t += 2) {
    GITER(t,     avX, bvX, avY, bvY, 1, 1, 6, (void)0);
    GITER(t + 1, avY, bvY, avX, bvX, 1, 1, 6, (void)0);
  }
  // Iter 28: last staging (tile 31).
  GITER(28, avX, bvX, avY, bvY, 1, 1, 6, (void)0);
  // Iter 29: sA[2] free -> ifeats rows 128..191 (IF1 = 4 loads/thread).
  GITER(29, avY, bvY, avX, bvX, 1, 0, 4,
        if_stage(128); if_stage(144); if_stage(160); if_stage(176));
  // Iter 30: sA[0]+sB[0] free -> rows 0..63, 192..223 (IF2 = 6).
  GITER(30, avX, bvX, avY, bvY, 1, 0, 10,
        if_stage(0); if_stage(16); if_stage(32); if_stage(48);
        if_stage(192); if_stage(208));
  // Iter 31: sA[1]+sB[1] free -> rows 64..127, 224..255 (IF3 = 6).
  GITER(31, avY, bvY, avX, bvX, 0, 0, 0,
        if_stage(64); if_stage(80); if_stage(96); if_stage(112);
        if_stage(224); if_stage(240));

  // epilogue: C/D layout col=lane&15, row=quad*4+reg; ifeats from LDS.
#pragma unroll
  for (int nt = 0; nt < 4; ++nt) {
    int col = j0 + wn + nt * 16 + r16;
    int c_in = wn + nt * 16 + r16;          // 0..127 within tile
    int g = c_in >> 2;                      // 16B chunk index (0..31)
    float bias = b2[col];
#pragma unroll
    for (int mt = 0; mt < 4; ++mt) {
      int rbase = i0 + wm + mt * 16 + quad * 4;
      int rloc = wm + mt * 16 + quad * 4;   // 0..255 within tile
#pragma unroll
      for (int r = 0; r < 4; ++r) {
        int row = rloc + r;
        const float* fp = (const float*)&smem[row * 256 +
                                              ((g ^ (row & 7)) << 3) +
                                              ((c_in & 3) << 1)];
        size_t idx = (size_t)(rbase + r) * DIMD + col;
        out[idx] = *fp + bias + acc[mt][nt][r];
      }
    }
  }
}

// ---------------------------------------------------------------------------
extern "C" void kernel_launch(void* const* d_in, const int* in_sizes, int n_in,
                              void* d_out, int out_size, void* d_ws, size_t ws_size,
                              hipStream_t stream) {
  const float* ifeats = (const float*)d_in[0];
  const float* tn     = (const float*)d_in[1];
  const float* ta     = (const float*)d_in[2];
  const float* cw     = (const float*)d_in[3];
  const float* cb     = (const float*)d_in[4];
  const float* w2     = (const float*)d_in[5];
  const float* b2     = (const float*)d_in[6];
  float* out = (float*)d_out;

  // ws: [0, 4MB) w2 bf16 | [4MB, 36MB) x2 bf16
  u16* w2b = (u16*)d_ws;
  u16* x2  = (u16*)((char*)d_ws + (size_t)DIMD * KDIM * 2);

  pre_kernel<<<2048, 256, 0, stream>>>(ifeats, tn, ta, cw, cb, w2, x2, w2b);
  gemm_bt<<<256, 512, 0, stream>>>(x2, w2b, ifeats, b2, out);
}